// Round 16
// baseline (175.386 us; speedup 1.0000x reference)
//
#include <hip/hip_runtime.h>
#include <hip/hip_fp16.h>

// GCN: h1 = relu(agg(x@W1)); h2 = relu(agg(h1@W2)); out = h2@Wfc + bfc
// out_i = relu( dinv_i * (sum_j y_j + y_i) + b ),  y = (x@W)*dinv[:,None]
// R16 = R15 (best: 172.5us, MFMA gemms) + ET=2048 (391 blocks: at ET=4096
// only 196 blocks ran -> 60 CUs idle in hist/scatter) + k_prep folded into
// k_hist as 48 prep-only blocks (uniform per-block branch; one fewer launch).
// Lessons: R3/R5 atomic floor; R4 TLP collapse; R7 VGPR caps; R10 barriers;
// R12/R13 plane-split loses (aggs are L3 random-line-service bound).

#define CAP   64        // per-node CSR capacity (Poisson(16), max ~35)
#define NBUK  196       // buckets: dst>>8, dst < 50176
#define ET    2048      // edges per block in hist/scatter
#define NB    391       // ceil(800000/2048)
#define NPREP 48        // extra prep-only blocks appended to k_hist

typedef unsigned short u16;
typedef unsigned long long u64;
typedef _Float16 f16;
typedef _Float16 f16x8 __attribute__((ext_vector_type(8)));
typedef float f32x4 __attribute__((ext_vector_type(4)));

// blocks [0,NB): per-block bucket histogram of dst (plain stores).
// blocks [NB,NB+NPREP): W1/W2 -> f16 transposed [n][k] (fused k_prep).
__global__ __launch_bounds__(256) void k_hist(const int* __restrict__ dst,
                                              int* __restrict__ blkcnt,
                                              const float* __restrict__ W1,
                                              const float* __restrict__ W2,
                                              f16* __restrict__ W1t,
                                              f16* __restrict__ W2t, int E) {
    const int tid = threadIdx.x, blk = blockIdx.x;
    if (blk >= NB) {   // prep-only blocks: uniform branch, no barriers crossed
        int i = (blk - NB) * 256 + tid;
        if (i < 128 * 64) {
            int k = i >> 6, nn = i & 63;
            W1t[nn * 128 + k] = (f16)W1[k * 64 + nn];
        }
        int j = i - 128 * 64;
        if (j >= 0 && j < 64 * 64) {
            int k = j >> 6, nn = j & 63;
            W2t[nn * 64 + k] = (f16)W2[k * 64 + nn];
        }
        return;
    }
    __shared__ int hist[NBUK];
    for (int i = tid; i < NBUK; i += 256) hist[i] = 0;
    __syncthreads();
    const int e0 = blk * ET;
    if (e0 + ET <= E) {
        const int4* d4 = (const int4*)(dst + e0);
#pragma unroll
        for (int j = 0; j < ET / 1024; j++) {
            int4 d = d4[j * 256 + tid];
            atomicAdd(&hist[(unsigned)d.x >> 8], 1);
            atomicAdd(&hist[(unsigned)d.y >> 8], 1);
            atomicAdd(&hist[(unsigned)d.z >> 8], 1);
            atomicAdd(&hist[(unsigned)d.w >> 8], 1);
        }
    } else {
        for (int j = 0; j < ET / 256; j++) {
            int e = e0 + j * 256 + tid;
            if (e < E) atomicAdd(&hist[(unsigned)dst[e] >> 8], 1);
        }
    }
    __syncthreads();
    for (int b = tid; b < NBUK; b += 256) blkcnt[b * NB + blk] = hist[b];
}

// one block per bucket: exclusive scan of blkcnt[b][0..NB), total -> btot[b]
// (512-thread Hillis-Steele; NB=391 <= 512 -- R8-proven variant)
__global__ __launch_bounds__(512) void k_scanA(int* __restrict__ blkcnt,
                                               int* __restrict__ btot) {
    __shared__ int s[512];
    const int t = threadIdx.x, b = blockIdx.x;
    int v = (t < NB) ? blkcnt[b * NB + t] : 0;
    s[t] = v;
    __syncthreads();
#pragma unroll
    for (int d = 1; d < 512; d <<= 1) {
        int u = (t >= d) ? s[t - d] : 0;
        __syncthreads();
        s[t] += u;
        __syncthreads();
    }
    if (t < NB) blkcnt[b * NB + t] = s[t] - v;   // exclusive
    if (t == 511) btot[b] = s[511];
}

// exclusive scan of btot[NBUK] into bb[] (LDS). Barrier-uniform for any
// blockDim >= 256 (R10 lesson: all threads execute all __syncthreads).
__device__ __forceinline__ void local_bucket_scan(const int* __restrict__ btot,
                                                  int* bb, int tid) {
    if (tid < 256) bb[tid] = (tid < NBUK) ? btot[tid] : 0;
    __syncthreads();
#pragma unroll
    for (int d = 1; d < 256; d <<= 1) {
        int u = 0;
        if (tid < 256 && tid >= d) u = bb[tid - d];
        __syncthreads();
        if (tid < 256) bb[tid] += u;
        __syncthreads();
    }
    if (tid < 256) bb[tid] -= (tid < NBUK) ? btot[tid] : 0;   // exclusive
    __syncthreads();
}

// read src+dst, pack inline, scatter into bucket-grouped eb via LDS cursors.
__global__ __launch_bounds__(256) void k_scatter(const int* __restrict__ src,
                                                 const int* __restrict__ dst,
                                                 const int* __restrict__ blkcnt,
                                                 const int* __restrict__ btot,
                                                 unsigned* __restrict__ eb, int E) {
    __shared__ int bb[256];
    __shared__ int cur[NBUK];
    const int tid = threadIdx.x, blk = blockIdx.x;
    local_bucket_scan(btot, bb, tid);
    for (int i = tid; i < NBUK; i += 256) cur[i] = blkcnt[i * NB + blk] + bb[i];
    __syncthreads();
    const int e0 = blk * ET;
    if (e0 + ET <= E) {
        const int4* s4 = (const int4*)(src + e0);
        const int4* d4 = (const int4*)(dst + e0);
#pragma unroll
        for (int j = 0; j < ET / 1024; j++) {
            int4 sv = s4[j * 256 + tid];
            int4 dv = d4[j * 256 + tid];
            unsigned u0 = ((unsigned)dv.x << 16) | (unsigned)sv.x;
            unsigned u1 = ((unsigned)dv.y << 16) | (unsigned)sv.y;
            unsigned u2 = ((unsigned)dv.z << 16) | (unsigned)sv.z;
            unsigned u3 = ((unsigned)dv.w << 16) | (unsigned)sv.w;
            eb[atomicAdd(&cur[u0 >> 24], 1)] = u0;
            eb[atomicAdd(&cur[u1 >> 24], 1)] = u1;
            eb[atomicAdd(&cur[u2 >> 24], 1)] = u2;
            eb[atomicAdd(&cur[u3 >> 24], 1)] = u3;
        }
    } else {
        for (int j = 0; j < ET / 256; j++) {
            int e = e0 + j * 256 + tid;
            if (e < E) {
                unsigned d = (unsigned)dst[e];
                unsigned u = (d << 16) | (unsigned)src[e];
                eb[atomicAdd(&cur[d >> 8], 1)] = u;
            }
        }
    }
}

// one wg per bucket: CAP-padded ushort CSR rows in LDS, coalesced writeback.
__global__ __launch_bounds__(1024) void k_buildb(const unsigned* __restrict__ eb,
                                                 const int* __restrict__ btot,
                                                 u16* __restrict__ csr,
                                                 int* __restrict__ cnt, int n) {
    __shared__ int bb[256];
    __shared__ u16 lcsr[256 * CAP];   // 32 KB
    __shared__ int cur[256];
    const int tid = threadIdx.x, b = blockIdx.x;
    local_bucket_scan(btot, bb, tid);   // barrier-uniform (all 1024 threads)
    if (tid < 256) cur[tid] = 0;
    __syncthreads();
    const int e0 = bb[b], e1 = bb[b] + btot[b];
    for (int e = e0 + tid; e < e1; e += 1024) {
        unsigned u = __builtin_nontemporal_load(eb + e);
        int ld = (int)((u >> 16) & 255u);
        int p = atomicAdd(&cur[ld], 1);           // LDS atomic
        if (p < CAP) lcsr[ld * CAP + p] = (u16)(u & 0xffffu);
    }
    __syncthreads();
    const int node0 = b * 256;
    for (int i = tid; i < 256 * CAP / 8; i += 1024) {   // uint4 = 8 u16
        int r = i / (CAP / 8), q = i % (CAP / 8);
        int c = cur[r] < CAP ? cur[r] : CAP;
        uint4 v = *(uint4*)&lcsr[r * CAP + q * 8];
        if (q * 8 >= c) v = make_uint4(0, 0, 0, 0);
        *(uint4*)&csr[(size_t)(node0 + r) * CAP + q * 8] = v;
    }
    if (tid < 256 && node0 + tid < n) cnt[node0 + tid] = cur[tid];
}

// MFMA gemm: Y[row][c] = fp16( dinv[row] * sum_k X[row][k] * W[k][c] ).
// 64x64 tile, 256 thr = 4 waves; wave w -> rows 16w..16w+15, 4 col-tiles.
// Whole K staged once. Wt is f16 [64][K] (n-major). Verified layouts
// (m89/m91/m120): A[m=lane&15][k=quad*8+j]; B[n=lane&15][k=quad*8+j];
// C/D col=lane&15, row=quad*4+reg.
template <int K, bool IS_HALF, typename TIN>
__global__ __launch_bounds__(256) void k_gemm(const TIN* __restrict__ X,
                                              const f16* __restrict__ Wt,
                                              const int* __restrict__ cnt,
                                              __half* __restrict__ Y, int n) {
    constexpr int KS = K + 8;
    __shared__ f16 xsh[64 * KS];
    __shared__ f16 wsh[64 * KS];
    const int tid = threadIdx.x;
    const int row0 = blockIdx.x * 64;

    for (int i = tid; i < 64 * (K / 8); i += 256) {
        int nn = i / (K / 8), kq = i % (K / 8);
        *(uint4*)&wsh[nn * KS + 8 * kq] = *(const uint4*)&Wt[nn * K + 8 * kq];
    }
    if constexpr (IS_HALF) {
        const __half* Xh = (const __half*)X;
        for (int i = tid; i < 64 * (K / 8); i += 256) {
            int r = i / (K / 8), kq = i % (K / 8);
            uint4 u = make_uint4(0, 0, 0, 0);     // 0x0000 == +0.0h
            int row = row0 + r;
            if (row < n) u = *(const uint4*)&Xh[(size_t)row * K + 8 * kq];
            *(uint4*)&xsh[r * KS + 8 * kq] = u;
        }
    } else {
        const float* Xf = (const float*)X;
        for (int i = tid; i < 64 * (K / 4); i += 256) {
            int r = i / (K / 4), q4 = i % (K / 4);
            float4 v = make_float4(0.f, 0.f, 0.f, 0.f);
            int row = row0 + r;
            if (row < n) v = *(const float4*)&Xf[(size_t)row * K + 4 * q4];
            __half2 p0 = __floats2half2_rn(v.x, v.y);
            __half2 p1 = __floats2half2_rn(v.z, v.w);
            uint2 o = make_uint2(*(unsigned*)&p0, *(unsigned*)&p1);
            *(uint2*)&xsh[r * KS + 4 * q4] = o;
        }
    }
    __syncthreads();

    const int wv = tid >> 6;        // wave id 0..3
    const int lane = tid & 63;
    const int mn = lane & 15;       // m (A rows / D cols)
    const int q = lane >> 4;        // quad 0..3

    f32x4 acc[4] = {{0, 0, 0, 0}, {0, 0, 0, 0}, {0, 0, 0, 0}, {0, 0, 0, 0}};
    const f16* arow = &xsh[(16 * wv + mn) * KS + 8 * q];
#pragma unroll
    for (int s = 0; s < K / 32; s++) {
        f16x8 A = *(const f16x8*)&arow[32 * s];
#pragma unroll
        for (int c = 0; c < 4; c++) {
            f16x8 B = *(const f16x8*)&wsh[(16 * c + mn) * KS + 32 * s + 8 * q];
            acc[c] = __builtin_amdgcn_mfma_f32_16x16x32_f16(A, B, acc[c], 0, 0, 0);
        }
    }

    // epilogue: lane holds D[row = 16wv + 4q + r][col = 16c + mn]
    const int rowb = row0 + 16 * wv + 4 * q;
    float dinv[4];
#pragma unroll
    for (int r = 0; r < 4; r++)
        dinv[r] = rsqrtf((float)((rowb + r < n) ? cnt[rowb + r] : 0) + 1.0f);
#pragma unroll
    for (int c = 0; c < 4; c++)
#pragma unroll
        for (int r = 0; r < 4; r++) {
            int row = rowb + r;
            if (row < n)
                Y[(size_t)row * 64 + 16 * c + mn] = __float2half(acc[c][r] * dinv[r]);
        }
}

// gather-sum over neighbors; quarter-wave of 16 lanes per node, lane = 4 feats
// (uint2 = half4 per row-load -> one wave vmem instr fetches 4 rows).
// Index loads NONTEMPORAL (csr streamed once/agg; keep L2 for y rows).
__device__ __forceinline__ float4 gather_node(const __half* __restrict__ y,
                                              const u16* __restrict__ lst,
                                              int deg, int c4) {
    float4 a0 = make_float4(0.f, 0.f, 0.f, 0.f);
    float4 a1 = make_float4(0.f, 0.f, 0.f, 0.f);
    int i = 0;
    for (; i + 16 <= deg; i += 16) {
        const u64* lp = (const u64*)(lst + i);
        u64 q0 = __builtin_nontemporal_load(lp);
        u64 q1 = __builtin_nontemporal_load(lp + 1);
        u64 q2 = __builtin_nontemporal_load(lp + 2);
        u64 q3 = __builtin_nontemporal_load(lp + 3);
        unsigned idx[16];
#pragma unroll
        for (int t = 0; t < 4; t++) {
            idx[t]      = (unsigned)((q0 >> (16 * t)) & 0xffffu);
            idx[t + 4]  = (unsigned)((q1 >> (16 * t)) & 0xffffu);
            idx[t + 8]  = (unsigned)((q2 >> (16 * t)) & 0xffffu);
            idx[t + 12] = (unsigned)((q3 >> (16 * t)) & 0xffffu);
        }
        uint2 v[16];
#pragma unroll
        for (int t = 0; t < 16; t++) v[t] = *(const uint2*)&y[(size_t)idx[t] * 64 + 4 * c4];
#pragma unroll
        for (int t = 0; t < 16; t += 2) {
            float2 lo0 = __half22float2(*(__half2*)&v[t].x);
            float2 hi0 = __half22float2(*(__half2*)&v[t].y);
            float2 lo1 = __half22float2(*(__half2*)&v[t + 1].x);
            float2 hi1 = __half22float2(*(__half2*)&v[t + 1].y);
            a0.x += lo0.x; a0.y += lo0.y; a0.z += hi0.x; a0.w += hi0.y;
            a1.x += lo1.x; a1.y += lo1.y; a1.z += hi1.x; a1.w += hi1.y;
        }
    }
    if (i + 8 <= deg) {
        const u64* lp = (const u64*)(lst + i);
        u64 q0 = __builtin_nontemporal_load(lp);
        u64 q1 = __builtin_nontemporal_load(lp + 1);
        unsigned idx[8];
#pragma unroll
        for (int t = 0; t < 4; t++) {
            idx[t]     = (unsigned)((q0 >> (16 * t)) & 0xffffu);
            idx[t + 4] = (unsigned)((q1 >> (16 * t)) & 0xffffu);
        }
        uint2 v[8];
#pragma unroll
        for (int t = 0; t < 8; t++) v[t] = *(const uint2*)&y[(size_t)idx[t] * 64 + 4 * c4];
#pragma unroll
        for (int t = 0; t < 8; t += 2) {
            float2 lo0 = __half22float2(*(__half2*)&v[t].x);
            float2 hi0 = __half22float2(*(__half2*)&v[t].y);
            float2 lo1 = __half22float2(*(__half2*)&v[t + 1].x);
            float2 hi1 = __half22float2(*(__half2*)&v[t + 1].y);
            a0.x += lo0.x; a0.y += lo0.y; a0.z += hi0.x; a0.w += hi0.y;
            a1.x += lo1.x; a1.y += lo1.y; a1.z += hi1.x; a1.w += hi1.y;
        }
        i += 8;
    }
    if (i + 4 <= deg) {
        u64 q0 = __builtin_nontemporal_load((const u64*)(lst + i));
        unsigned idx[4];
#pragma unroll
        for (int t = 0; t < 4; t++) idx[t] = (unsigned)((q0 >> (16 * t)) & 0xffffu);
        uint2 v[4];
#pragma unroll
        for (int t = 0; t < 4; t++) v[t] = *(const uint2*)&y[(size_t)idx[t] * 64 + 4 * c4];
#pragma unroll
        for (int t = 0; t < 4; t += 2) {
            float2 lo0 = __half22float2(*(__half2*)&v[t].x);
            float2 hi0 = __half22float2(*(__half2*)&v[t].y);
            float2 lo1 = __half22float2(*(__half2*)&v[t + 1].x);
            float2 hi1 = __half22float2(*(__half2*)&v[t + 1].y);
            a0.x += lo0.x; a0.y += lo0.y; a0.z += hi0.x; a0.w += hi0.y;
            a1.x += lo1.x; a1.y += lo1.y; a1.z += hi1.x; a1.w += hi1.y;
        }
        i += 4;
    }
    for (; i < deg; i++) {
        uint2 vv = *(const uint2*)&y[(size_t)lst[i] * 64 + 4 * c4];
        float2 lo = __half22float2(*(__half2*)&vv.x);
        float2 hi = __half22float2(*(__half2*)&vv.y);
        a0.x += lo.x; a0.y += lo.y; a0.z += hi.x; a0.w += hi.y;
    }
    return make_float4(a0.x + a1.x, a0.y + a1.y, a0.z + a1.z, a0.w + a1.w);
}

// layer-1 agg: h1[i] = fp16( relu( dinv_i*(sum_j y_j + y_i) + b ) )
// 256 thr = 16 nodes/block; h1 store nontemporal (not re-read until gemm2).
__global__ __launch_bounds__(256) void k_agg1(const __half* __restrict__ y,
                                              const u16* __restrict__ csr,
                                              const int* __restrict__ cnt,
                                              const float* __restrict__ bias,
                                              __half* __restrict__ h1, int n) {
    const int tid = threadIdx.x;
    const int c4 = tid & 15;
    const int node = blockIdx.x * 16 + (tid >> 4);
    if (node >= n) return;
    int deg_raw = cnt[node];
    int deg = deg_raw > CAP ? CAP : deg_raw;
    float4 acc = gather_node(y, csr + node * CAP, deg, c4);
    uint2 sv = *(const uint2*)&y[(size_t)node * 64 + 4 * c4];
    float2 slo = __half22float2(*(__half2*)&sv.x);
    float2 shi = __half22float2(*(__half2*)&sv.y);
    float d = rsqrtf((float)deg_raw + 1.0f);
    float4 bv = *(const float4*)&bias[4 * c4];
    float v0 = fmaxf(fmaf(d, acc.x + slo.x, bv.x), 0.f);
    float v1 = fmaxf(fmaf(d, acc.y + slo.y, bv.y), 0.f);
    float v2 = fmaxf(fmaf(d, acc.z + shi.x, bv.z), 0.f);
    float v3 = fmaxf(fmaf(d, acc.w + shi.y, bv.w), 0.f);
    __half2 o0 = __floats2half2_rn(v0, v1);
    __half2 o1 = __floats2half2_rn(v2, v3);
    u64 packed = (u64)(*(unsigned*)&o0) | ((u64)(*(unsigned*)&o1) << 32);
    __builtin_nontemporal_store(packed, (u64*)&h1[(size_t)node * 64 + 4 * c4]);
}

// layer-2 agg + fused FC: out[i][c] = sum_k relu(...)_k * Wfc[k][c] + bfc[c]
// h2 stays in f32 registers. Wfc transposed in LDS; 16-lane xor butterflies.
__global__ __launch_bounds__(256) void k_agg2fc(const __half* __restrict__ y,
                                                const u16* __restrict__ csr,
                                                const int* __restrict__ cnt,
                                                const float* __restrict__ bias,
                                                const float* __restrict__ Wfc,
                                                const float* __restrict__ bfc,
                                                float* __restrict__ out, int n) {
    __shared__ float wf[12 * 64];   // transposed: wf[c*64 + k] = Wfc[k*12+c]
    __shared__ float bf[12];
    const int tid = threadIdx.x;
    for (int i = tid; i < 12 * 64; i += 256) {
        int c = i >> 6, k = i & 63;
        wf[i] = Wfc[k * 12 + c];
    }
    if (tid < 12) bf[tid] = bfc[tid];
    __syncthreads();

    const int c4 = tid & 15;
    const int node = blockIdx.x * 16 + (tid >> 4);
    if (node >= n) return;
    int deg_raw = cnt[node];
    int deg = deg_raw > CAP ? CAP : deg_raw;
    float4 acc = gather_node(y, csr + node * CAP, deg, c4);
    uint2 sv = *(const uint2*)&y[(size_t)node * 64 + 4 * c4];
    float2 slo = __half22float2(*(__half2*)&sv.x);
    float2 shi = __half22float2(*(__half2*)&sv.y);
    float d = rsqrtf((float)deg_raw + 1.0f);
    float4 bv = *(const float4*)&bias[4 * c4];
    float v0 = fmaxf(fmaf(d, acc.x + slo.x, bv.x), 0.f);
    float v1 = fmaxf(fmaf(d, acc.y + slo.y, bv.y), 0.f);
    float v2 = fmaxf(fmaf(d, acc.z + shi.x, bv.z), 0.f);
    float v3 = fmaxf(fmaf(d, acc.w + shi.y, bv.w), 0.f);

    // FC: 12 xor-butterfly reductions over the 16-lane quarter-wave
    float res = 0.f;
#pragma unroll
    for (int c = 0; c < 12; c++) {
        float4 wv = *(const float4*)&wf[c * 64 + 4 * c4];
        float p = v0 * wv.x + v1 * wv.y + v2 * wv.z + v3 * wv.w;
        p += __shfl_xor(p, 1);
        p += __shfl_xor(p, 2);
        p += __shfl_xor(p, 4);
        p += __shfl_xor(p, 8);
        if (c4 == c) res = p + bf[c];
    }
    if (c4 < 12) out[(size_t)node * 12 + c4] = res;
}

extern "C" void kernel_launch(void* const* d_in, const int* in_sizes, int n_in,
                              void* d_out, int out_size, void* d_ws, size_t ws_size,
                              hipStream_t stream) {
    const float* x   = (const float*)d_in[0];
    const int*   ei  = (const int*)d_in[1];
    const float* W1  = (const float*)d_in[2];
    const float* b1  = (const float*)d_in[3];
    const float* W2  = (const float*)d_in[4];
    const float* b2  = (const float*)d_in[5];
    const float* Wfc = (const float*)d_in[6];
    const float* bfc = (const float*)d_in[7];
    float* out = (float*)d_out;

    const int n = in_sizes[0] / 128;   // 50000
    const int E = in_sizes[1] / 2;     // 800000
    const int* src = ei;
    const int* dst = ei + E;

    char* w = (char*)d_ws;
    unsigned* eb  = (unsigned*)w;  w += (size_t)((E + 63) / 64) * 64 * 4;    // 3.2 MB
    int* blkcnt   = (int*)w;       w += (size_t)NBUK * NB * 4 + 256;         // 306 KB
    int* btot     = (int*)w;       w += 256 * 4;
    int* cnt      = (int*)w;       w += (size_t)((n + 63) / 64) * 64 * 4;
    f16* W1t      = (f16*)w;       w += 128 * 64 * 2;                        // 16 KB
    f16* W2t      = (f16*)w;       w += 64 * 64 * 2 + 256;                   // 8 KB
    u16* csr      = (u16*)w;       w += (size_t)NBUK * 256 * CAP * 2;        // 6.4 MB
    __half* y     = (__half*)w;    w += (size_t)n * 64 * 2;                  // 6.4 MB
    __half* h1    = (__half*)w;                                              // 6.4 MB

    k_hist   <<<dim3(NB + NPREP), dim3(256), 0, stream>>>(dst, blkcnt, W1, W2, W1t, W2t, E);
    k_scanA  <<<dim3(NBUK), dim3(512), 0, stream>>>(blkcnt, btot);
    k_scatter<<<dim3(NB), dim3(256), 0, stream>>>(src, dst, blkcnt, btot, eb, E);
    k_buildb <<<dim3(NBUK), dim3(1024), 0, stream>>>(eb, btot, csr, cnt, n);
    k_gemm<128, false, float><<<dim3((n + 63) / 64), dim3(256), 0, stream>>>(x, W1t, cnt, y, n);
    k_agg1   <<<dim3((n + 15) / 16), dim3(256), 0, stream>>>(y, csr, cnt, b1, h1, n);
    k_gemm<64, true, __half><<<dim3((n + 63) / 64), dim3(256), 0, stream>>>(h1, W2t, cnt, y, n);
    k_agg2fc <<<dim3((n + 15) / 16), dim3(256), 0, stream>>>(y, csr, cnt, b2, Wfc, bfc, out, n);
}

// Round 17
// 173.355 us; speedup vs baseline: 1.0117x; 1.0117x over previous
//
#include <hip/hip_runtime.h>
#include <hip/hip_fp16.h>

// GCN: h1 = relu(agg(x@W1)); h2 = relu(agg(h1@W2)); out = h2@Wfc + bfc
// out_i = relu( dinv_i * (sum_j y_j + y_i) + b ),  y = (x@W)*dinv[:,None]
// R17 = R15 verbatim (best: 172.5us). R16's ET=2048 + fused-prep regressed
// (+2.9us: scatter is per-block-overhead bound, not occupancy bound).
// Structure: atomic-free bucketed CSR build -> MFMA f16 gemms (fp32 accum)
// -> quarter-wave gather aggs (nontemporal index streams, fp16 y/h1).
// Lessons: R3/R5 device-atomic floor ~52us; R4 TLP collapse; R7 VGPR caps;
// R10 uniform barriers; R12/R13 plane-split loses (aggs L3-service-bound);
// R16 more blocks != faster when per-block fixed cost dominates.

#define CAP   64        // per-node CSR capacity (Poisson(16), max ~35)
#define NBUK  196       // buckets: dst>>8, dst < 50176
#define ET    4096      // edges per block in hist/scatter
#define NB    196       // ceil(800000/4096)

typedef unsigned short u16;
typedef unsigned long long u64;
typedef _Float16 f16;
typedef _Float16 f16x8 __attribute__((ext_vector_type(8)));
typedef float f32x4 __attribute__((ext_vector_type(4)));

// one-time per launch: W1 (128x64), W2 (64x64) -> f16 transposed [n][k]
__global__ __launch_bounds__(256) void k_prep(const float* __restrict__ W1,
                                              const float* __restrict__ W2,
                                              f16* __restrict__ W1t,
                                              f16* __restrict__ W2t) {
    int i = blockIdx.x * 256 + threadIdx.x;
    if (i < 128 * 64) {
        int k = i >> 6, nn = i & 63;
        W1t[nn * 128 + k] = (f16)W1[k * 64 + nn];
    }
    int j = i - 128 * 64;
    if (j >= 0 && j < 64 * 64) {
        int k = j >> 6, nn = j & 63;
        W2t[nn * 64 + k] = (f16)W2[k * 64 + nn];
    }
}

// per-block bucket histogram of dst (plain stores, no device atomics)
__global__ __launch_bounds__(256) void k_hist(const int* __restrict__ dst,
                                              int* __restrict__ blkcnt, int E) {
    __shared__ int hist[NBUK];
    const int tid = threadIdx.x, blk = blockIdx.x;
    for (int i = tid; i < NBUK; i += 256) hist[i] = 0;
    __syncthreads();
    const int e0 = blk * ET;
    if (e0 + ET <= E) {
        const int4* d4 = (const int4*)(dst + e0);
#pragma unroll
        for (int j = 0; j < ET / 1024; j++) {
            int4 d = d4[j * 256 + tid];
            atomicAdd(&hist[(unsigned)d.x >> 8], 1);
            atomicAdd(&hist[(unsigned)d.y >> 8], 1);
            atomicAdd(&hist[(unsigned)d.z >> 8], 1);
            atomicAdd(&hist[(unsigned)d.w >> 8], 1);
        }
    } else {
        for (int j = 0; j < ET / 256; j++) {
            int e = e0 + j * 256 + tid;
            if (e < E) atomicAdd(&hist[(unsigned)dst[e] >> 8], 1);
        }
    }
    __syncthreads();
    for (int b = tid; b < NBUK; b += 256) blkcnt[b * NB + blk] = hist[b];
}

// one block per bucket: exclusive scan of blkcnt[b][0..NB), total -> btot[b]
__global__ __launch_bounds__(256) void k_scanA(int* __restrict__ blkcnt,
                                               int* __restrict__ btot) {
    __shared__ int s[256];
    const int t = threadIdx.x, b = blockIdx.x;
    int v = (t < NB) ? blkcnt[b * NB + t] : 0;
    s[t] = v;
    __syncthreads();
#pragma unroll
    for (int d = 1; d < 256; d <<= 1) {
        int u = (t >= d) ? s[t - d] : 0;
        __syncthreads();
        s[t] += u;
        __syncthreads();
    }
    if (t < NB) blkcnt[b * NB + t] = s[t] - v;   // exclusive
    if (t == 255) btot[b] = s[255];
}

// exclusive scan of btot[NBUK] into bb[] (LDS). Barrier-uniform for any
// blockDim >= 256 (R10 lesson: all threads execute all __syncthreads).
__device__ __forceinline__ void local_bucket_scan(const int* __restrict__ btot,
                                                  int* bb, int tid) {
    if (tid < 256) bb[tid] = (tid < NBUK) ? btot[tid] : 0;
    __syncthreads();
#pragma unroll
    for (int d = 1; d < 256; d <<= 1) {
        int u = 0;
        if (tid < 256 && tid >= d) u = bb[tid - d];
        __syncthreads();
        if (tid < 256) bb[tid] += u;
        __syncthreads();
    }
    if (tid < 256) bb[tid] -= (tid < NBUK) ? btot[tid] : 0;   // exclusive
    __syncthreads();
}

// read src+dst, pack inline, scatter into bucket-grouped eb via LDS cursors.
__global__ __launch_bounds__(256) void k_scatter(const int* __restrict__ src,
                                                 const int* __restrict__ dst,
                                                 const int* __restrict__ blkcnt,
                                                 const int* __restrict__ btot,
                                                 unsigned* __restrict__ eb, int E) {
    __shared__ int bb[256];
    __shared__ int cur[NBUK];
    const int tid = threadIdx.x, blk = blockIdx.x;
    local_bucket_scan(btot, bb, tid);
    for (int i = tid; i < NBUK; i += 256) cur[i] = blkcnt[i * NB + blk] + bb[i];
    __syncthreads();
    const int e0 = blk * ET;
    if (e0 + ET <= E) {
        const int4* s4 = (const int4*)(src + e0);
        const int4* d4 = (const int4*)(dst + e0);
#pragma unroll
        for (int j = 0; j < ET / 1024; j++) {
            int4 sv = s4[j * 256 + tid];
            int4 dv = d4[j * 256 + tid];
            unsigned u0 = ((unsigned)dv.x << 16) | (unsigned)sv.x;
            unsigned u1 = ((unsigned)dv.y << 16) | (unsigned)sv.y;
            unsigned u2 = ((unsigned)dv.z << 16) | (unsigned)sv.z;
            unsigned u3 = ((unsigned)dv.w << 16) | (unsigned)sv.w;
            eb[atomicAdd(&cur[u0 >> 24], 1)] = u0;
            eb[atomicAdd(&cur[u1 >> 24], 1)] = u1;
            eb[atomicAdd(&cur[u2 >> 24], 1)] = u2;
            eb[atomicAdd(&cur[u3 >> 24], 1)] = u3;
        }
    } else {
        for (int j = 0; j < ET / 256; j++) {
            int e = e0 + j * 256 + tid;
            if (e < E) {
                unsigned d = (unsigned)dst[e];
                unsigned u = (d << 16) | (unsigned)src[e];
                eb[atomicAdd(&cur[d >> 8], 1)] = u;
            }
        }
    }
}

// one wg per bucket: CAP-padded ushort CSR rows in LDS, coalesced writeback.
__global__ __launch_bounds__(1024) void k_buildb(const unsigned* __restrict__ eb,
                                                 const int* __restrict__ btot,
                                                 u16* __restrict__ csr,
                                                 int* __restrict__ cnt, int n) {
    __shared__ int bb[256];
    __shared__ u16 lcsr[256 * CAP];   // 32 KB
    __shared__ int cur[256];
    const int tid = threadIdx.x, b = blockIdx.x;
    local_bucket_scan(btot, bb, tid);   // barrier-uniform (all 1024 threads)
    if (tid < 256) cur[tid] = 0;
    __syncthreads();
    const int e0 = bb[b], e1 = bb[b] + btot[b];
    for (int e = e0 + tid; e < e1; e += 1024) {
        unsigned u = __builtin_nontemporal_load(eb + e);
        int ld = (int)((u >> 16) & 255u);
        int p = atomicAdd(&cur[ld], 1);           // LDS atomic
        if (p < CAP) lcsr[ld * CAP + p] = (u16)(u & 0xffffu);
    }
    __syncthreads();
    const int node0 = b * 256;
    for (int i = tid; i < 256 * CAP / 8; i += 1024) {   // uint4 = 8 u16
        int r = i / (CAP / 8), q = i % (CAP / 8);
        int c = cur[r] < CAP ? cur[r] : CAP;
        uint4 v = *(uint4*)&lcsr[r * CAP + q * 8];
        if (q * 8 >= c) v = make_uint4(0, 0, 0, 0);
        *(uint4*)&csr[(size_t)(node0 + r) * CAP + q * 8] = v;
    }
    if (tid < 256 && node0 + tid < n) cnt[node0 + tid] = cur[tid];
}

// MFMA gemm: Y[row][c] = fp16( dinv[row] * sum_k X[row][k] * W[k][c] ).
// 64x64 tile, 256 thr = 4 waves; wave w -> rows 16w..16w+15, 4 col-tiles.
// Whole K staged once. Wt is f16 [64][K] (n-major). Verified layouts
// (m89/m91/m120): A[m=lane&15][k=quad*8+j]; B[n=lane&15][k=quad*8+j];
// C/D col=lane&15, row=quad*4+reg.
template <int K, bool IS_HALF, typename TIN>
__global__ __launch_bounds__(256) void k_gemm(const TIN* __restrict__ X,
                                              const f16* __restrict__ Wt,
                                              const int* __restrict__ cnt,
                                              __half* __restrict__ Y, int n) {
    constexpr int KS = K + 8;
    __shared__ f16 xsh[64 * KS];
    __shared__ f16 wsh[64 * KS];
    const int tid = threadIdx.x;
    const int row0 = blockIdx.x * 64;

    for (int i = tid; i < 64 * (K / 8); i += 256) {
        int nn = i / (K / 8), kq = i % (K / 8);
        *(uint4*)&wsh[nn * KS + 8 * kq] = *(const uint4*)&Wt[nn * K + 8 * kq];
    }
    if constexpr (IS_HALF) {
        const __half* Xh = (const __half*)X;
        for (int i = tid; i < 64 * (K / 8); i += 256) {
            int r = i / (K / 8), kq = i % (K / 8);
            uint4 u = make_uint4(0, 0, 0, 0);     // 0x0000 == +0.0h
            int row = row0 + r;
            if (row < n) u = *(const uint4*)&Xh[(size_t)row * K + 8 * kq];
            *(uint4*)&xsh[r * KS + 8 * kq] = u;
        }
    } else {
        const float* Xf = (const float*)X;
        for (int i = tid; i < 64 * (K / 4); i += 256) {
            int r = i / (K / 4), q4 = i % (K / 4);
            float4 v = make_float4(0.f, 0.f, 0.f, 0.f);
            int row = row0 + r;
            if (row < n) v = *(const float4*)&Xf[(size_t)row * K + 4 * q4];
            __half2 p0 = __floats2half2_rn(v.x, v.y);
            __half2 p1 = __floats2half2_rn(v.z, v.w);
            uint2 o = make_uint2(*(unsigned*)&p0, *(unsigned*)&p1);
            *(uint2*)&xsh[r * KS + 4 * q4] = o;
        }
    }
    __syncthreads();

    const int wv = tid >> 6;        // wave id 0..3
    const int lane = tid & 63;
    const int mn = lane & 15;       // m (A rows / D cols)
    const int q = lane >> 4;        // quad 0..3

    f32x4 acc[4] = {{0, 0, 0, 0}, {0, 0, 0, 0}, {0, 0, 0, 0}, {0, 0, 0, 0}};
    const f16* arow = &xsh[(16 * wv + mn) * KS + 8 * q];
#pragma unroll
    for (int s = 0; s < K / 32; s++) {
        f16x8 A = *(const f16x8*)&arow[32 * s];
#pragma unroll
        for (int c = 0; c < 4; c++) {
            f16x8 B = *(const f16x8*)&wsh[(16 * c + mn) * KS + 32 * s + 8 * q];
            acc[c] = __builtin_amdgcn_mfma_f32_16x16x32_f16(A, B, acc[c], 0, 0, 0);
        }
    }

    // epilogue: lane holds D[row = 16wv + 4q + r][col = 16c + mn]
    const int rowb = row0 + 16 * wv + 4 * q;
    float dinv[4];
#pragma unroll
    for (int r = 0; r < 4; r++)
        dinv[r] = rsqrtf((float)((rowb + r < n) ? cnt[rowb + r] : 0) + 1.0f);
#pragma unroll
    for (int c = 0; c < 4; c++)
#pragma unroll
        for (int r = 0; r < 4; r++) {
            int row = rowb + r;
            if (row < n)
                Y[(size_t)row * 64 + 16 * c + mn] = __float2half(acc[c][r] * dinv[r]);
        }
}

// gather-sum over neighbors; quarter-wave of 16 lanes per node, lane = 4 feats
// (uint2 = half4 per row-load -> one wave vmem instr fetches 4 rows).
// Index loads NONTEMPORAL (csr streamed once/agg; keep L2 for y rows).
__device__ __forceinline__ float4 gather_node(const __half* __restrict__ y,
                                              const u16* __restrict__ lst,
                                              int deg, int c4) {
    float4 a0 = make_float4(0.f, 0.f, 0.f, 0.f);
    float4 a1 = make_float4(0.f, 0.f, 0.f, 0.f);
    int i = 0;
    for (; i + 16 <= deg; i += 16) {
        const u64* lp = (const u64*)(lst + i);
        u64 q0 = __builtin_nontemporal_load(lp);
        u64 q1 = __builtin_nontemporal_load(lp + 1);
        u64 q2 = __builtin_nontemporal_load(lp + 2);
        u64 q3 = __builtin_nontemporal_load(lp + 3);
        unsigned idx[16];
#pragma unroll
        for (int t = 0; t < 4; t++) {
            idx[t]      = (unsigned)((q0 >> (16 * t)) & 0xffffu);
            idx[t + 4]  = (unsigned)((q1 >> (16 * t)) & 0xffffu);
            idx[t + 8]  = (unsigned)((q2 >> (16 * t)) & 0xffffu);
            idx[t + 12] = (unsigned)((q3 >> (16 * t)) & 0xffffu);
        }
        uint2 v[16];
#pragma unroll
        for (int t = 0; t < 16; t++) v[t] = *(const uint2*)&y[(size_t)idx[t] * 64 + 4 * c4];
#pragma unroll
        for (int t = 0; t < 16; t += 2) {
            float2 lo0 = __half22float2(*(__half2*)&v[t].x);
            float2 hi0 = __half22float2(*(__half2*)&v[t].y);
            float2 lo1 = __half22float2(*(__half2*)&v[t + 1].x);
            float2 hi1 = __half22float2(*(__half2*)&v[t + 1].y);
            a0.x += lo0.x; a0.y += lo0.y; a0.z += hi0.x; a0.w += hi0.y;
            a1.x += lo1.x; a1.y += lo1.y; a1.z += hi1.x; a1.w += hi1.y;
        }
    }
    if (i + 8 <= deg) {
        const u64* lp = (const u64*)(lst + i);
        u64 q0 = __builtin_nontemporal_load(lp);
        u64 q1 = __builtin_nontemporal_load(lp + 1);
        unsigned idx[8];
#pragma unroll
        for (int t = 0; t < 4; t++) {
            idx[t]     = (unsigned)((q0 >> (16 * t)) & 0xffffu);
            idx[t + 4] = (unsigned)((q1 >> (16 * t)) & 0xffffu);
        }
        uint2 v[8];
#pragma unroll
        for (int t = 0; t < 8; t++) v[t] = *(const uint2*)&y[(size_t)idx[t] * 64 + 4 * c4];
#pragma unroll
        for (int t = 0; t < 8; t += 2) {
            float2 lo0 = __half22float2(*(__half2*)&v[t].x);
            float2 hi0 = __half22float2(*(__half2*)&v[t].y);
            float2 lo1 = __half22float2(*(__half2*)&v[t + 1].x);
            float2 hi1 = __half22float2(*(__half2*)&v[t + 1].y);
            a0.x += lo0.x; a0.y += lo0.y; a0.z += hi0.x; a0.w += hi0.y;
            a1.x += lo1.x; a1.y += lo1.y; a1.z += hi1.x; a1.w += hi1.y;
        }
        i += 8;
    }
    if (i + 4 <= deg) {
        u64 q0 = __builtin_nontemporal_load((const u64*)(lst + i));
        unsigned idx[4];
#pragma unroll
        for (int t = 0; t < 4; t++) idx[t] = (unsigned)((q0 >> (16 * t)) & 0xffffu);
        uint2 v[4];
#pragma unroll
        for (int t = 0; t < 4; t++) v[t] = *(const uint2*)&y[(size_t)idx[t] * 64 + 4 * c4];
#pragma unroll
        for (int t = 0; t < 4; t += 2) {
            float2 lo0 = __half22float2(*(__half2*)&v[t].x);
            float2 hi0 = __half22float2(*(__half2*)&v[t].y);
            float2 lo1 = __half22float2(*(__half2*)&v[t + 1].x);
            float2 hi1 = __half22float2(*(__half2*)&v[t + 1].y);
            a0.x += lo0.x; a0.y += lo0.y; a0.z += hi0.x; a0.w += hi0.y;
            a1.x += lo1.x; a1.y += lo1.y; a1.z += hi1.x; a1.w += hi1.y;
        }
        i += 4;
    }
    for (; i < deg; i++) {
        uint2 vv = *(const uint2*)&y[(size_t)lst[i] * 64 + 4 * c4];
        float2 lo = __half22float2(*(__half2*)&vv.x);
        float2 hi = __half22float2(*(__half2*)&vv.y);
        a0.x += lo.x; a0.y += lo.y; a0.z += hi.x; a0.w += hi.y;
    }
    return make_float4(a0.x + a1.x, a0.y + a1.y, a0.z + a1.z, a0.w + a1.w);
}

// layer-1 agg: h1[i] = fp16( relu( dinv_i*(sum_j y_j + y_i) + b ) )
// 256 thr = 16 nodes/block; h1 store nontemporal (not re-read until gemm2).
__global__ __launch_bounds__(256) void k_agg1(const __half* __restrict__ y,
                                              const u16* __restrict__ csr,
                                              const int* __restrict__ cnt,
                                              const float* __restrict__ bias,
                                              __half* __restrict__ h1, int n) {
    const int tid = threadIdx.x;
    const int c4 = tid & 15;
    const int node = blockIdx.x * 16 + (tid >> 4);
    if (node >= n) return;
    int deg_raw = cnt[node];
    int deg = deg_raw > CAP ? CAP : deg_raw;
    float4 acc = gather_node(y, csr + node * CAP, deg, c4);
    uint2 sv = *(const uint2*)&y[(size_t)node * 64 + 4 * c4];
    float2 slo = __half22float2(*(__half2*)&sv.x);
    float2 shi = __half22float2(*(__half2*)&sv.y);
    float d = rsqrtf((float)deg_raw + 1.0f);
    float4 bv = *(const float4*)&bias[4 * c4];
    float v0 = fmaxf(fmaf(d, acc.x + slo.x, bv.x), 0.f);
    float v1 = fmaxf(fmaf(d, acc.y + slo.y, bv.y), 0.f);
    float v2 = fmaxf(fmaf(d, acc.z + shi.x, bv.z), 0.f);
    float v3 = fmaxf(fmaf(d, acc.w + shi.y, bv.w), 0.f);
    __half2 o0 = __floats2half2_rn(v0, v1);
    __half2 o1 = __floats2half2_rn(v2, v3);
    u64 packed = (u64)(*(unsigned*)&o0) | ((u64)(*(unsigned*)&o1) << 32);
    __builtin_nontemporal_store(packed, (u64*)&h1[(size_t)node * 64 + 4 * c4]);
}

// layer-2 agg + fused FC: out[i][c] = sum_k relu(...)_k * Wfc[k][c] + bfc[c]
// h2 stays in f32 registers. Wfc transposed in LDS; 16-lane xor butterflies.
__global__ __launch_bounds__(256) void k_agg2fc(const __half* __restrict__ y,
                                                const u16* __restrict__ csr,
                                                const int* __restrict__ cnt,
                                                const float* __restrict__ bias,
                                                const float* __restrict__ Wfc,
                                                const float* __restrict__ bfc,
                                                float* __restrict__ out, int n) {
    __shared__ float wf[12 * 64];   // transposed: wf[c*64 + k] = Wfc[k*12+c]
    __shared__ float bf[12];
    const int tid = threadIdx.x;
    for (int i = tid; i < 12 * 64; i += 256) {
        int c = i >> 6, k = i & 63;
        wf[i] = Wfc[k * 12 + c];
    }
    if (tid < 12) bf[tid] = bfc[tid];
    __syncthreads();

    const int c4 = tid & 15;
    const int node = blockIdx.x * 16 + (tid >> 4);
    if (node >= n) return;
    int deg_raw = cnt[node];
    int deg = deg_raw > CAP ? CAP : deg_raw;
    float4 acc = gather_node(y, csr + node * CAP, deg, c4);
    uint2 sv = *(const uint2*)&y[(size_t)node * 64 + 4 * c4];
    float2 slo = __half22float2(*(__half2*)&sv.x);
    float2 shi = __half22float2(*(__half2*)&sv.y);
    float d = rsqrtf((float)deg_raw + 1.0f);
    float4 bv = *(const float4*)&bias[4 * c4];
    float v0 = fmaxf(fmaf(d, acc.x + slo.x, bv.x), 0.f);
    float v1 = fmaxf(fmaf(d, acc.y + slo.y, bv.y), 0.f);
    float v2 = fmaxf(fmaf(d, acc.z + shi.x, bv.z), 0.f);
    float v3 = fmaxf(fmaf(d, acc.w + shi.y, bv.w), 0.f);

    // FC: 12 xor-butterfly reductions over the 16-lane quarter-wave
    float res = 0.f;
#pragma unroll
    for (int c = 0; c < 12; c++) {
        float4 wv = *(const float4*)&wf[c * 64 + 4 * c4];
        float p = v0 * wv.x + v1 * wv.y + v2 * wv.z + v3 * wv.w;
        p += __shfl_xor(p, 1);
        p += __shfl_xor(p, 2);
        p += __shfl_xor(p, 4);
        p += __shfl_xor(p, 8);
        if (c4 == c) res = p + bf[c];
    }
    if (c4 < 12) out[(size_t)node * 12 + c4] = res;
}

extern "C" void kernel_launch(void* const* d_in, const int* in_sizes, int n_in,
                              void* d_out, int out_size, void* d_ws, size_t ws_size,
                              hipStream_t stream) {
    const float* x   = (const float*)d_in[0];
    const int*   ei  = (const int*)d_in[1];
    const float* W1  = (const float*)d_in[2];
    const float* b1  = (const float*)d_in[3];
    const float* W2  = (const float*)d_in[4];
    const float* b2  = (const float*)d_in[5];
    const float* Wfc = (const float*)d_in[6];
    const float* bfc = (const float*)d_in[7];
    float* out = (float*)d_out;

    const int n = in_sizes[0] / 128;   // 50000
    const int E = in_sizes[1] / 2;     // 800000
    const int* src = ei;
    const int* dst = ei + E;
    const int nblk = (E + ET - 1) / ET;   // 196

    char* w = (char*)d_ws;
    unsigned* eb  = (unsigned*)w;  w += (size_t)((E + 63) / 64) * 64 * 4;    // 3.2 MB
    int* blkcnt   = (int*)w;       w += (size_t)NBUK * NB * 4 + 256;
    int* btot     = (int*)w;       w += 256 * 4;
    int* cnt      = (int*)w;       w += (size_t)((n + 63) / 64) * 64 * 4;
    f16* W1t      = (f16*)w;       w += 128 * 64 * 2;                        // 16 KB
    f16* W2t      = (f16*)w;       w += 64 * 64 * 2 + 256;                   // 8 KB
    u16* csr      = (u16*)w;       w += (size_t)NBUK * 256 * CAP * 2;        // 6.4 MB
    __half* y     = (__half*)w;    w += (size_t)n * 64 * 2;                  // 6.4 MB
    __half* h1    = (__half*)w;                                              // 6.4 MB

    k_prep   <<<dim3(48), dim3(256), 0, stream>>>(W1, W2, W1t, W2t);
    k_hist   <<<dim3(nblk), dim3(256), 0, stream>>>(dst, blkcnt, E);
    k_scanA  <<<dim3(NBUK), dim3(256), 0, stream>>>(blkcnt, btot);
    k_scatter<<<dim3(nblk), dim3(256), 0, stream>>>(src, dst, blkcnt, btot, eb, E);
    k_buildb <<<dim3(NBUK), dim3(1024), 0, stream>>>(eb, btot, csr, cnt, n);
    k_gemm<128, false, float><<<dim3((n + 63) / 64), dim3(256), 0, stream>>>(x, W1t, cnt, y, n);
    k_agg1   <<<dim3((n + 15) / 16), dim3(256), 0, stream>>>(y, csr, cnt, b1, h1, n);
    k_gemm<64, true, __half><<<dim3((n + 63) / 64), dim3(256), 0, stream>>>(h1, W2t, cnt, y, n);
    k_agg2fc <<<dim3((n + 15) / 16), dim3(256), 0, stream>>>(y, csr, cnt, b2, Wfc, bfc, out, n);
}